// Round 2
// baseline (130.898 us; speedup 1.0000x reference)
//
#include <hip/hip_runtime.h>
#include <math.h>

// Leaky integrator scan, emulating the reference's SEQUENTIAL FP32 rounding.
//
// Step: s' = (x >= 0.5) ? s + x : max(0, s - 0.01), computed in fp32.
// Once s is large, fl(s + a) == s + g*rnd(a/g) with g = ulp-grid of s's binade
// (s is always a multiple of g). So the sequential-fp32 effect of a chunk on a
// large state is a plain sum of QUANTIZED increments, independent of s.
// We therefore compute per-chunk aggregates for each candidate grid, pick the
// grid per chunk from an approximate (exact-sum) trajectory, scan the selected
// aggregates for chunk-start states, and emit per-element with plain fp32 ops
// (which auto-quantize at large s exactly like the reference).

#define BLOCK 256
#define PER_THREAD 16
#define CHUNK (BLOCK * PER_THREAD)   // 4096 elements per chunk/block
#define NGRID 7                      // binades e=17..23 -> g = 2^-6 .. 1

struct FnAB { float a, b; };         // s -> max(s + a, b)

__device__ __forceinline__ FnAB fn_identity() { FnAB r; r.a = 0.0f; r.b = -INFINITY; return r; }

// f earlier, g later
__device__ __forceinline__ FnAB fn_combine(FnAB f, FnAB g) {
    FnAB r;
    r.a = f.a + g.a;
    r.b = fmaxf(f.b + g.a, g.b);
    return r;
}

__device__ __forceinline__ void fn_push(FnAB& t, float xv) {
    bool fire = (xv >= 0.5f);
    float a  = fire ? xv : -0.01f;
    float be = fire ? -INFINITY : 0.0f;
    t.b = fmaxf(t.b + a, be);
    t.a = t.a + a;
}

// ---------------- Kernel A: per-chunk exact fn + quantized sums ----------------
struct Acc { FnAB ex; float q[NGRID]; };

__global__ __launch_bounds__(BLOCK) void kA(const float* __restrict__ x,
                                            float* __restrict__ ws, int n, int nb) {
    __shared__ Acc sh[BLOCK];
    const float gtab[NGRID]  = {0.015625f, 0.03125f, 0.0625f, 0.125f, 0.25f, 0.5f, 1.0f};
    const float igtab[NGRID] = {64.0f, 32.0f, 16.0f, 8.0f, 4.0f, 2.0f, 1.0f};

    int base = blockIdx.x * CHUNK + threadIdx.x * PER_THREAD;
    Acc t;
    t.ex = fn_identity();
#pragma unroll
    for (int k = 0; k < NGRID; ++k) t.q[k] = 0.0f;

    auto push = [&](float xv) {
        bool fire = (xv >= 0.5f);
        float a  = fire ? xv : -0.01f;
        float be = fire ? -INFINITY : 0.0f;
        t.ex.b = fmaxf(t.ex.b + a, be);
        t.ex.a += a;
#pragma unroll
        for (int k = 0; k < NGRID; ++k)
            t.q[k] = fmaf(gtab[k], rintf(a * igtab[k]), t.q[k]);
    };

    if (base + PER_THREAD <= n) {
#pragma unroll
        for (int j = 0; j < PER_THREAD / 4; ++j) {
            float4 v = reinterpret_cast<const float4*>(x + base)[j];
            push(v.x); push(v.y); push(v.z); push(v.w);
        }
    } else {
        for (int j = 0; j < PER_THREAD; ++j) {
            int idx = base + j;
            if (idx < n) push(x[idx]);
        }
    }

    sh[threadIdx.x] = t;
    // order-preserving tree reduction
    for (int s = 1; s < BLOCK; s <<= 1) {
        __syncthreads();
        if ((threadIdx.x & (2 * s - 1)) == 0 && threadIdx.x + s < BLOCK) {
            Acc g = sh[threadIdx.x + s];
            Acc f = sh[threadIdx.x];
            f.ex = fn_combine(f.ex, g.ex);
#pragma unroll
            for (int k = 0; k < NGRID; ++k) f.q[k] += g.q[k];
            sh[threadIdx.x] = f;
        }
    }
    __syncthreads();
    if (threadIdx.x == 0) {
        int b = blockIdx.x;
        ws[0 * nb + b] = sh[0].ex.a;
        ws[1 * nb + b] = sh[0].ex.b;
#pragma unroll
        for (int k = 0; k < NGRID; ++k) ws[(2 + k) * nb + b] = sh[0].q[k];
    }
}

// ---------------- Kernel B: grid selection + scan -> chunk-start states ----------------
__device__ __forceinline__ FnAB pick_fn(float s, float aex, float bex,
                                        const float* __restrict__ ws, int c, int nb) {
    FnAB r;
    if (s >= 131072.0f) {   // 2^17: quantization starts to matter
        int E = (int)(__float_as_uint(s) >> 23) - 127;   // binade exponent
        int k = E - 17;
        if (k > NGRID - 1) k = NGRID - 1;
        r.a = ws[(2 + k) * nb + c];
        r.b = -INFINITY;    // clamp never active at s >= 2^17
    } else {
        r.a = aex; r.b = bex;
    }
    return r;
}

__global__ __launch_bounds__(BLOCK) void kB(const float* __restrict__ ws,
                                            float* __restrict__ s_start, int nb) {
    __shared__ float sa[BLOCK], sb[BLOCK];
    int tid = threadIdx.x;
    int per = (nb + BLOCK - 1) / BLOCK;
    int start = tid * per;

    // ---- phase 1: scan of EXACT fns -> per-thread exclusive exact prefix
    FnAB t = fn_identity();
    for (int j = 0; j < per; ++j) {
        int c = start + j;
        if (c < nb) { FnAB e; e.a = ws[c]; e.b = ws[nb + c]; t = fn_combine(t, e); }
    }
    sa[tid] = t.a; sb[tid] = t.b;
    __syncthreads();
    for (int off = 1; off < BLOCK; off <<= 1) {
        float va = sa[tid], vb = sb[tid];
        float na = va, nb_ = vb;
        if (tid >= off) { na = sa[tid - off] + va; nb_ = fmaxf(sb[tid - off] + va, vb); }
        __syncthreads();
        sa[tid] = na; sb[tid] = nb_;
        __syncthreads();
    }
    FnAB exE;
    if (tid == 0) exE = fn_identity(); else { exE.a = sa[tid - 1]; exE.b = sb[tid - 1]; }
    __syncthreads();

    // ---- phase 2: per-chunk grid selection, scan of SELECTED fns
    FnAB re = exE;
    FnAB st = fn_identity();
    for (int j = 0; j < per; ++j) {
        int c = start + j;
        if (c >= nb) break;
        float aex = ws[c], bex = ws[nb + c];
        float scur = fmaxf(re.a, re.b);            // approx state at chunk start (s0=0)
        FnAB sel = pick_fn(scur, aex, bex, ws, c, nb);
        st = fn_combine(st, sel);
        FnAB e; e.a = aex; e.b = bex;
        re = fn_combine(re, e);
    }
    sa[tid] = st.a; sb[tid] = st.b;
    __syncthreads();
    for (int off = 1; off < BLOCK; off <<= 1) {
        float va = sa[tid], vb = sb[tid];
        float na = va, nb_ = vb;
        if (tid >= off) { na = sa[tid - off] + va; nb_ = fmaxf(sb[tid - off] + va, vb); }
        __syncthreads();
        sa[tid] = na; sb[tid] = nb_;
        __syncthreads();
    }
    FnAB exS;
    if (tid == 0) exS = fn_identity(); else { exS.a = sa[tid - 1]; exS.b = sb[tid - 1]; }

    // ---- phase 3: emit chunk-start states of the SELECTED (quantized) scan
    re = exE;
    FnAB rs = exS;
    for (int j = 0; j < per; ++j) {
        int c = start + j;
        if (c >= nb) break;
        float aex = ws[c], bex = ws[nb + c];
        float scur = fmaxf(re.a, re.b);
        FnAB sel = pick_fn(scur, aex, bex, ws, c, nb);
        s_start[c] = fmaxf(rs.a, rs.b);            // state entering chunk c
        rs = fn_combine(rs, sel);
        FnAB e; e.a = aex; e.b = bex;
        re = fn_combine(re, e);
    }
}

// ---------------- Kernel C: apply chunk-start state, emit outputs ----------------
__global__ __launch_bounds__(BLOCK) void kC(const float* __restrict__ x,
                                            const float* __restrict__ s_start,
                                            float* __restrict__ out, int n) {
    __shared__ float sa[BLOCK], sb[BLOCK];
    int tid = threadIdx.x;
    int base = blockIdx.x * CHUNK + tid * PER_THREAD;
    bool full = (base + PER_THREAD <= n);

    float xs[PER_THREAD];
    FnAB t = fn_identity();
    if (full) {
#pragma unroll
        for (int j = 0; j < PER_THREAD / 4; ++j) {
            float4 v = reinterpret_cast<const float4*>(x + base)[j];
            xs[4 * j + 0] = v.x; xs[4 * j + 1] = v.y;
            xs[4 * j + 2] = v.z; xs[4 * j + 3] = v.w;
        }
#pragma unroll
        for (int j = 0; j < PER_THREAD; ++j) fn_push(t, xs[j]);
    } else {
        for (int j = 0; j < PER_THREAD; ++j) {
            int idx = base + j;
            if (idx < n) { xs[j] = x[idx]; fn_push(t, xs[j]); }
            else xs[j] = 0.0f;
        }
    }

    sa[tid] = t.a; sb[tid] = t.b;
    __syncthreads();
    for (int off = 1; off < BLOCK; off <<= 1) {
        float va = sa[tid], vb = sb[tid];
        float na = va, nb_ = vb;
        if (tid >= off) { na = sa[tid - off] + va; nb_ = fmaxf(sb[tid - off] + va, vb); }
        __syncthreads();
        sa[tid] = na; sb[tid] = nb_;
        __syncthreads();
    }
    FnAB ex;
    if (tid == 0) ex = fn_identity(); else { ex.a = sa[tid - 1]; ex.b = sb[tid - 1]; }

    float s0c = s_start[blockIdx.x];
    float s = fmaxf(s0c + ex.a, ex.b);   // state entering this thread's run

    // per-element walk with PLAIN fp32 ops: at large s these auto-round onto
    // the binade grid, exactly matching the sequential reference.
    if (full) {
        float outs[PER_THREAD];
#pragma unroll
        for (int j = 0; j < PER_THREAD; ++j) {
            float xv = xs[j];
            float acc = s + xv;
            float dec = fmaxf(0.0f, s - 0.01f);
            s = (xv >= 0.5f) ? acc : dec;
            outs[j] = s;
        }
#pragma unroll
        for (int j = 0; j < PER_THREAD / 4; ++j) {
            reinterpret_cast<float4*>(out + base)[j] =
                make_float4(outs[4 * j + 0], outs[4 * j + 1], outs[4 * j + 2], outs[4 * j + 3]);
        }
    } else {
        for (int j = 0; j < PER_THREAD; ++j) {
            int idx = base + j;
            if (idx < n) {
                float xv = xs[j];
                float acc = s + xv;
                float dec = fmaxf(0.0f, s - 0.01f);
                s = (xv >= 0.5f) ? acc : dec;
                out[idx] = s;
            }
        }
    }
}

extern "C" void kernel_launch(void* const* d_in, const int* in_sizes, int n_in,
                              void* d_out, int out_size, void* d_ws, size_t ws_size,
                              hipStream_t stream) {
    const float* x = (const float*)d_in[0];
    float* out = (float*)d_out;
    int n = in_sizes[0];
    int nb = (n + CHUNK - 1) / CHUNK;

    float* ws      = (float*)d_ws;        // (2 + NGRID) * nb aggregates, SoA
    float* s_start = ws + (2 + NGRID) * nb;  // nb chunk-start states

    kA<<<nb, BLOCK, 0, stream>>>(x, ws, n, nb);
    kB<<<1, BLOCK, 0, stream>>>(ws, s_start, nb);
    kC<<<nb, BLOCK, 0, stream>>>(x, s_start, out, n);
}